// Round 1
// baseline (1396.064 us; speedup 1.0000x reference)
//
#include <hip/hip_runtime.h>
#include <math.h>

#define NLEV 16
#define TBL (1u << 19)
#define TMASK (TBL - 1u)

struct ScaleArgs { float s[NLEV]; };

__global__ __launch_bounds__(256)
void hashenc(const float* __restrict__ x, const float* __restrict__ W,
             float* __restrict__ out, ScaleArgs sc, int N)
{
    int n = blockIdx.x * blockDim.x + threadIdx.x;
    if (n >= N) return;

    float px = x[(size_t)n * 3 + 0];
    float py = x[(size_t)n * 3 + 1];
    float pz = x[(size_t)n * 3 + 2];

    float acc[2 * NLEV];

    #pragma unroll
    for (int l = 0; l < NLEV; ++l) {
        float s = sc.s[l];
        float ux = px * s, uy = py * s, uz = pz * s;
        int ix = (int)ux, iy = (int)uy, iz = (int)uz;   // trunc == floor (x >= 0)
        float dx = ux - (float)ix;
        float dy = uy - (float)iy;
        float dz = uz - (float)iz;

        // hash parts: prod0 = ix*1, prod1 = iy*P1 (int32 wrap), prod2 = iz*P2
        unsigned a0 = (unsigned)ix;
        unsigned a1 = (unsigned)iy * 2654435761u;
        unsigned a2 = (unsigned)iz * 805459861u;
        unsigned b0 = a0 + 1u;
        unsigned b1 = a1 + 2654435761u;
        unsigned b2 = a2 + 805459861u;

        const float* Wl = W + (size_t)l * TBL * 2u;
        float ax = 0.f, ay = 0.f;

        #pragma unroll
        for (int v = 0; v < 8; ++v) {
            unsigned h = ((v & 1) ? b0 : a0) ^ ((v & 2) ? b1 : a1) ^ ((v & 4) ? b2 : a2);
            h &= TMASK;
            // BIN_MASK true (corner bit clear) -> floor corner -> weight (1-diff)
            float wx = (v & 1) ? dx : 1.f - dx;
            float wy = (v & 2) ? dy : 1.f - dy;
            float wz = (v & 4) ? dz : 1.f - dz;
            float w = (wx * wy) * wz;   // matches wts.prod(axis=-1) left fold
            const float2 fv = *reinterpret_cast<const float2*>(Wl + (size_t)h * 2u);
            ax = fmaf(fv.x, w, ax);
            ay = fmaf(fv.y, w, ay);
        }
        acc[2 * l + 0] = ax;
        acc[2 * l + 1] = ay;
    }

    // write the 128B output row as 8 x float4
    float4* o = reinterpret_cast<float4*>(out + (size_t)n * (2 * NLEV));
    #pragma unroll
    for (int j = 0; j < 8; ++j) {
        o[j] = make_float4(acc[4 * j + 0], acc[4 * j + 1],
                           acc[4 * j + 2], acc[4 * j + 3]);
    }
}

extern "C" void kernel_launch(void* const* d_in, const int* in_sizes, int n_in,
                              void* d_out, int out_size, void* d_ws, size_t ws_size,
                              hipStream_t stream) {
    const float* x = (const float*)d_in[0];
    const float* W = (const float*)d_in[1];
    float* out = (float*)d_out;
    int N = in_sizes[0] / 3;

    // replicate numpy: b = exp((log(2048)-log(16))/16); scale_l = float32(16 * b**l)
    ScaleArgs sc;
    double b = exp((log(2048.0) - log(16.0)) / 16.0);
    for (int l = 0; l < NLEV; ++l) {
        double p;
        switch (l) {
            case 0: p = 1.0; break;
            case 1: p = b;   break;
            case 2: p = b * b; break;          // npy_pow shortcut for exponent 2
            default: p = pow(b, (double)l);    break;
        }
        sc.s[l] = (float)(16.0 * p);
    }

    int block = 256;
    int grid = (N + block - 1) / block;
    hipLaunchKernelGGL(hashenc, dim3(grid), dim3(block), 0, stream,
                       x, W, out, sc, N);
}